// Round 1
// baseline (47527.359 us; speedup 1.0000x reference)
//
#include <hip/hip_runtime.h>
#include <hip/hip_bf16.h>

// ---------------------------------------------------------------------------
// 2-layer LSTM (B=256, T=1024, H=256) persistent-cluster kernel.
//
// 8 independent clusters x 32 batch rows (batch is the only parallel dim that
// needs NO cross-cluster sync). Each cluster = 32 WGs; WG j owns 8 hidden
// units (32 gate cols: i,f,g,o x 8) of BOTH layers, weight slices resident in
// LDS (~50 KB bf16) for the entire kernel. Per timestep:
//   phase A: gates0 = h0 @ Whh0_sl (+ x*wih0 + b0), and layer1's h1 @ Whh1_sl
//            partial in the same pass; elementwise -> h0_new slice (bf16)
//   cluster barrier
//   phase B: gates1 += h0_new @ Wih1_sl (+ b1); elementwise -> h1_new slice;
//            out partial (fp32 h1_new) reduced over 8 lanes -> atomicAdd
//   cluster barrier
// h state double-buffered in workspace (bf16); cell state c stays WG-local in
// LDS fp32 (never communicated). Barrier slots use signed-diff phase compare:
// 0xAAAAAAAA poison and 0 both read as "not arrived" -> no init race.
// Agent-scope fences (buffer_wbl2/inv on gfx950) handle cross-XCD L2.
// ---------------------------------------------------------------------------

#define TT   1024   // timesteps
#define NC   8      // clusters
#define WPC  32     // workgroups per cluster
#define MR   32     // batch rows per cluster
#define NU   8      // hidden units per WG
#define NCOL 32     // gate cols per WG (4 gates x NU)
#define KP   264    // padded LDS K-stride (elems): 264*2B=528B -> 2-way-free banks

typedef __attribute__((ext_vector_type(8))) short  bfrag;  // 8 bf16 (4 VGPRs)
typedef __attribute__((ext_vector_type(4))) float  ffrag;  // 4 fp32 acc

__device__ __forceinline__ float sigf(float v) { return 1.0f / (1.0f + __expf(-v)); }
__device__ __forceinline__ float tanhfast(float v) {
    v = fminf(fmaxf(v, -15.f), 15.f);          // keep exp finite
    float e = __expf(2.0f * v);
    return (e - 1.0f) / (e + 1.0f);
}

__device__ __forceinline__ void cluster_barrier(int* slots, int j, int phase, int tid) {
    __syncthreads();
    __builtin_amdgcn_fence(__ATOMIC_RELEASE, "agent");   // flush my global writes (wbl2)
    if (tid == 0)
        __hip_atomic_store(&slots[j], phase, __ATOMIC_RELAXED, __HIP_MEMORY_SCOPE_AGENT);
    if (tid < WPC) {
        // signed diff: poison 0xAAAAAAAA and 0 are both < phase; bounded skew (+1) is >= 0
        while ((int)(__hip_atomic_load(&slots[tid], __ATOMIC_RELAXED, __HIP_MEMORY_SCOPE_AGENT) - phase) < 0)
            __builtin_amdgcn_s_sleep(2);
    }
    __builtin_amdgcn_fence(__ATOMIC_ACQUIRE, "agent");   // invalidate stale cached h (inv)
    __syncthreads();
}

__global__ void __launch_bounds__(256, 1)
lstm_kernel(const float* __restrict__ x,
            const float* __restrict__ Wih0, const float* __restrict__ Whh0,
            const float* __restrict__ bih0, const float* __restrict__ bhh0,
            const float* __restrict__ Wih1, const float* __restrict__ Whh1,
            const float* __restrict__ bih1, const float* __restrict__ bhh1,
            const float* __restrict__ Wlin, const float* __restrict__ blin,
            float* __restrict__ out, char* __restrict__ ws)
{
    const int tid = threadIdx.x;
    const int wg  = blockIdx.x;     // 0..255
    const int c   = wg >> 5;        // cluster 0..7
    const int j   = wg & 31;        // WG within cluster
    const int u0  = j * NU;         // first owned hidden unit

    int* slots = (int*)ws + c * 64;                        // 256B/cluster
    __hip_bfloat16* h0b = (__hip_bfloat16*)(ws + 4096);    // [2][NC][MR][256]
    __hip_bfloat16* h1b = h0b + 2 * NC * MR * 256;

    // ---- LDS ----
    __shared__ alignas(16) __hip_bfloat16 W0 [NCOL * KP];  // Whh0 slice [col][k]
    __shared__ alignas(16) __hip_bfloat16 W1i[NCOL * KP];  // Wih1 slice
    __shared__ alignas(16) __hip_bfloat16 W1h[NCOL * KP];  // Whh1 slice
    __shared__ float gbuf[MR * 33];                        // gate staging [m][col]
    __shared__ float cst0[MR * NU], cst1[MR * NU];         // cell states fp32
    __shared__ float bias0[NCOL], bias1[NCOL], wih0s[NCOL], wlins[NU];
    __shared__ float xcol[MR];
    __shared__ float blin_s;

    // ---- one-time init: weights -> LDS (fp32 -> bf16), zero state ----
    for (int i = tid; i < NCOL * 256; i += 256) {
        int n = i >> 8, k = i & 255;
        int r = (n >> 3) * 256 + u0 + (n & 7);     // global gate row
        W0 [n * KP + k] = __float2bfloat16(Whh0[r * 256 + k]);
        W1i[n * KP + k] = __float2bfloat16(Wih1[r * 256 + k]);
        W1h[n * KP + k] = __float2bfloat16(Whh1[r * 256 + k]);
    }
    if (tid < NCOL) {
        int r = (tid >> 3) * 256 + u0 + (tid & 7);
        bias0[tid] = bih0[r] + bhh0[r];
        bias1[tid] = bih1[r] + bhh1[r];
        wih0s[tid] = Wih0[r];
    }
    if (tid < NU) wlins[tid] = Wlin[u0 + tid];
    if (tid == 0) blin_s = blin[0];
    // zero my h slices of buffer 0 and my cell state
    {
        int m = tid >> 3, u = tid & 7;             // 256 threads == MR*NU
        h0b[((0 * NC + c) * MR + m) * 256 + u0 + u] = __float2bfloat16(0.f);
        h1b[((0 * NC + c) * MR + m) * 256 + u0 + u] = __float2bfloat16(0.f);
        cst0[tid] = 0.f; cst1[tid] = 0.f;
    }
    // zero my out columns (atomicAdd target; d_out is poisoned each call)
    for (int i = tid; i < MR * 32; i += 256) {
        int m = i >> 5, cc = i & 31;
        out[(c * MR + m) * TT + j * 32 + cc] = 0.f;
    }

    int ph = 1;
    cluster_barrier(slots, j, ph++, tid);

    // ---- wave / MFMA fragment geometry ----
    const int wave = tid >> 6, lane = tid & 63;
    const int mt = wave >> 1, nt = wave & 1;                 // 2x2 16x16 tiles
    const int arow = mt * 16 + (lane & 15);                  // batch row 0..31
    const int kq   = (lane >> 4) << 3;                       // k sub-offset
    const int bcol = nt * 16 + (lane & 15);                  // local gate col
    const int drow = mt * 16 + ((lane >> 4) << 2);           // D row base
    const int dcol = nt * 16 + (lane & 15);                  // D col
    const __hip_bfloat16* Bw0  = &W0 [bcol * KP];
    const __hip_bfloat16* Bw1i = &W1i[bcol * KP];
    const __hip_bfloat16* Bw1h = &W1h[bcol * KP];
    const int em = tid >> 3, eu = tid & 7;                   // elementwise (m,u)

    for (int t = 0; t < TT; ++t) {
        const int p = t & 1;
        const __hip_bfloat16* h0r = h0b + ((p * NC + c) * MR + arow) * 256;
        const __hip_bfloat16* h1r = h1b + ((p * NC + c) * MR + arow) * 256;

        // ===== phase A: layer0 gates + layer1 h1-partial (4 indep chains) =====
        ffrag a0a = {0.f,0.f,0.f,0.f}, a0b = {0.f,0.f,0.f,0.f};
        ffrag a1a = {0.f,0.f,0.f,0.f}, a1b = {0.f,0.f,0.f,0.f};
        #pragma unroll
        for (int ko = 0; ko < 256; ko += 64) {
            bfrag av0 = *(const bfrag*)(h0r + ko + kq);
            bfrag bv0 = *(const bfrag*)(Bw0 + ko + kq);
            a0a = __builtin_amdgcn_mfma_f32_16x16x32_bf16(av0, bv0, a0a, 0, 0, 0);
            bfrag av1 = *(const bfrag*)(h1r + ko + kq);
            bfrag bv1 = *(const bfrag*)(Bw1h + ko + kq);
            a1a = __builtin_amdgcn_mfma_f32_16x16x32_bf16(av1, bv1, a1a, 0, 0, 0);
            bfrag av2 = *(const bfrag*)(h0r + ko + 32 + kq);
            bfrag bv2 = *(const bfrag*)(Bw0 + ko + 32 + kq);
            a0b = __builtin_amdgcn_mfma_f32_16x16x32_bf16(av2, bv2, a0b, 0, 0, 0);
            bfrag av3 = *(const bfrag*)(h1r + ko + 32 + kq);
            bfrag bv3 = *(const bfrag*)(Bw1h + ko + 32 + kq);
            a1b = __builtin_amdgcn_mfma_f32_16x16x32_bf16(av3, bv3, a1b, 0, 0, 0);
        }
        a0a += a0b;
        if (tid < MR) xcol[tid] = x[(c * MR + tid) * TT + t];
        #pragma unroll
        for (int i = 0; i < 4; ++i) gbuf[(drow + i) * 33 + dcol] = a0a[i];
        __syncthreads();

        // elementwise layer0: thread = (m, u)
        {
            float xv = xcol[em];
            float gi = gbuf[em * 33 +      eu] + xv * wih0s[     eu] + bias0[     eu];
            float gf = gbuf[em * 33 +  8 + eu] + xv * wih0s[ 8 + eu] + bias0[ 8 + eu];
            float gg = gbuf[em * 33 + 16 + eu] + xv * wih0s[16 + eu] + bias0[16 + eu];
            float go = gbuf[em * 33 + 24 + eu] + xv * wih0s[24 + eu] + bias0[24 + eu];
            float cn = sigf(gf) * cst0[tid] + sigf(gi) * tanhfast(gg);
            cst0[tid] = cn;
            float hn = sigf(go) * tanhfast(cn);
            h0b[(((1 - p) * NC + c) * MR + em) * 256 + u0 + eu] = __float2bfloat16(hn);
        }
        cluster_barrier(slots, j, ph++, tid);

        // ===== phase B: layer1 gates += h0_new @ Wih1 =====
        const __hip_bfloat16* h0n = h0b + (((1 - p) * NC + c) * MR + arow) * 256;
        #pragma unroll
        for (int ko = 0; ko < 256; ko += 64) {
            bfrag av0 = *(const bfrag*)(h0n + ko + kq);
            bfrag bv0 = *(const bfrag*)(Bw1i + ko + kq);
            a1a = __builtin_amdgcn_mfma_f32_16x16x32_bf16(av0, bv0, a1a, 0, 0, 0);
            bfrag av1 = *(const bfrag*)(h0n + ko + 32 + kq);
            bfrag bv1 = *(const bfrag*)(Bw1i + ko + 32 + kq);
            a1b = __builtin_amdgcn_mfma_f32_16x16x32_bf16(av1, bv1, a1b, 0, 0, 0);
        }
        a1a += a1b;
        #pragma unroll
        for (int i = 0; i < 4; ++i) gbuf[(drow + i) * 33 + dcol] = a1a[i];
        __syncthreads();

        // elementwise layer1 + output partial
        {
            float gi = gbuf[em * 33 +      eu] + bias1[     eu];
            float gf = gbuf[em * 33 +  8 + eu] + bias1[ 8 + eu];
            float gg = gbuf[em * 33 + 16 + eu] + bias1[16 + eu];
            float go = gbuf[em * 33 + 24 + eu] + bias1[24 + eu];
            float cn = sigf(gf) * cst1[tid] + sigf(gi) * tanhfast(gg);
            cst1[tid] = cn;
            float hn = sigf(go) * tanhfast(cn);
            h1b[(((1 - p) * NC + c) * MR + em) * 256 + u0 + eu] = __float2bfloat16(hn);
            float pv = hn * wlins[eu];                       // fp32 h1 for output
            pv += __shfl_down(pv, 4, 8);
            pv += __shfl_down(pv, 2, 8);
            pv += __shfl_down(pv, 1, 8);
            if (eu == 0) {
                if (j == 0) pv += blin_s;                    // bias added exactly once
                atomicAdd(&out[(c * MR + em) * TT + t], pv);
            }
        }
        cluster_barrier(slots, j, ph++, tid);
    }
}

extern "C" void kernel_launch(void* const* d_in, const int* in_sizes, int n_in,
                              void* d_out, int out_size, void* d_ws, size_t ws_size,
                              hipStream_t stream)
{
    const float* x    = (const float*)d_in[0];
    const float* Wih0 = (const float*)d_in[1];
    const float* Whh0 = (const float*)d_in[2];
    const float* bih0 = (const float*)d_in[3];
    const float* bhh0 = (const float*)d_in[4];
    const float* Wih1 = (const float*)d_in[5];
    const float* Whh1 = (const float*)d_in[6];
    const float* bih1 = (const float*)d_in[7];
    const float* bhh1 = (const float*)d_in[8];
    const float* Wlin = (const float*)d_in[9];
    const float* blin = (const float*)d_in[10];
    float* out = (float*)d_out;
    char* ws   = (char*)d_ws;

    // 256 blocks x 256 threads: <=1 WG/CU worth of resources each, so all 256
    // are co-resident on 256 CUs (spin barriers safe without cooperative launch).
    lstm_kernel<<<dim3(256), dim3(256), 0, stream>>>(
        x, Wih0, Whh0, bih0, bhh0, Wih1, Whh1, bih1, bhh1, Wlin, blin, out, ws);
}

// Round 2
// 10197.033 us; speedup vs baseline: 4.6609x; 4.6609x over previous
//
#include <hip/hip_runtime.h>
#include <hip/hip_bf16.h>
#include <stdint.h>

// ---------------------------------------------------------------------------
// 2-layer LSTM (B=256, T=1024, H=256), persistent clusters, FENCE-FREE.
//
// 16 clusters x 16 batch rows; cluster = 16 WGs; WG j owns 16 hidden units
// (64 gate cols) of BOTH layers; weight slices LDS-resident (~101 KB).
// All cross-WG traffic (h state, flags, out partials) uses RELAXED agent-scope
// atomics -> global ops with sc1 that complete at the Infinity Cache (device
// coherence point). No agent fences (R1 showed fence = full L2 writeback =
// 2 MB/step HBM churn = 46 us/step). Ordering: s_waitcnt vmcnt(0) via inline
// asm before flag store; consumers read data only after flag load returns.
// Per step: phase A (gates0 = h0@Whh0 + x*wih0; g1 partial = h1@Whh1) ->
// barrier -> phase B (gates1 += h0n@Wih1; elementwise; publish h1 + out
// partials) -> barrier. Out reduced by WG0 one step later (fp32, no atomics
// on d_out). Cell state c never leaves the WG (LDS fp32).
// ---------------------------------------------------------------------------

#define TT   1024
#define NC   16     // clusters
#define WPC  16     // workgroups per cluster
#define MR   16     // batch rows per cluster
#define NU   16     // hidden units per WG
#define NCOL 64     // gate cols per WG (4 gates x NU)
#define KP   264    // padded LDS row stride in bf16 (528 B)

typedef __attribute__((ext_vector_type(8))) short  bfrag;  // 8 bf16
typedef __attribute__((ext_vector_type(4))) float  ffrag;  // 4 fp32

__device__ __forceinline__ float sigf(float v){ return 1.f/(1.f+__expf(-v)); }
__device__ __forceinline__ float tanhfast(float v){
    v = fminf(fmaxf(v,-15.f),15.f);
    float e = __expf(2.f*v);
    return (e-1.f)/(e+1.f);
}

__device__ __forceinline__ uint32_t ld_ic(const uint32_t* p){
    return __hip_atomic_load((uint32_t*)p, __ATOMIC_RELAXED, __HIP_MEMORY_SCOPE_AGENT);
}
__device__ __forceinline__ void st_ic(uint32_t* p, uint32_t v){
    __hip_atomic_store(p, v, __ATOMIC_RELAXED, __HIP_MEMORY_SCOPE_AGENT);
}
__device__ __forceinline__ float ldf_ic(const float* p){
    return __hip_atomic_load((float*)p, __ATOMIC_RELAXED, __HIP_MEMORY_SCOPE_AGENT);
}
__device__ __forceinline__ void stf_ic(float* p, float v){
    __hip_atomic_store(p, v, __ATOMIC_RELAXED, __HIP_MEMORY_SCOPE_AGENT);
}

// Fence-free cluster barrier: drain my vmem (stores reached IC), WG-sync,
// publish phase, spin on 16 flags (dependent IC load self-paces ~500cy).
__device__ __forceinline__ void cluster_barrier(int* slots, int j, int phase, int tid) {
    __asm__ volatile("s_waitcnt vmcnt(0)" ::: "memory");
    __syncthreads();
    if (tid == 0)
        __hip_atomic_store(&slots[j], phase, __ATOMIC_RELAXED, __HIP_MEMORY_SCOPE_AGENT);
    if (tid < WPC) {
        // signed diff: 0xAAAAAAAA poison and 0 both read as "not arrived"
        while ((int)(__hip_atomic_load(&slots[tid], __ATOMIC_RELAXED, __HIP_MEMORY_SCOPE_AGENT) - phase) < 0) {}
    }
    __asm__ volatile("" ::: "memory");
    __syncthreads();
}

__global__ void __launch_bounds__(256, 1)
lstm_kernel(const float* __restrict__ x,
            const float* __restrict__ Wih0, const float* __restrict__ Whh0,
            const float* __restrict__ bih0, const float* __restrict__ bhh0,
            const float* __restrict__ Wih1, const float* __restrict__ Whh1,
            const float* __restrict__ bih1, const float* __restrict__ bhh1,
            const float* __restrict__ Wlin, const float* __restrict__ blin,
            float* __restrict__ out, char* __restrict__ ws)
{
    const int tid = threadIdx.x;
    const int wg  = blockIdx.x;
    const int c   = wg >> 4;        // cluster 0..15
    const int j   = wg & 15;        // WG within cluster
    const int u0  = j * NU;

    int*      slots = (int*)ws + c * 64;                   // 16 KB total
    uint32_t* h0w   = (uint32_t*)(ws + 16384);             // [2][NC][MR][128] packed bf16x2
    uint32_t* h1w   = h0w + 2 * NC * MR * 128;
    float*    op    = (float*)(h1w + 2 * NC * MR * 128);   // out partials [2][NC][WPC][MR]

    // ---- LDS ----
    __shared__ alignas(16) __hip_bfloat16 W0 [NCOL*KP];
    __shared__ alignas(16) __hip_bfloat16 W1i[NCOL*KP];
    __shared__ alignas(16) __hip_bfloat16 W1h[NCOL*KP];
    __shared__ alignas(16) uint32_t hs0[MR*132];           // staged h (132 uint = 264 bf16 = KP)
    __shared__ alignas(16) uint32_t hs1[MR*132];
    __shared__ float gbuf[MR*68];
    __shared__ float cst0[256], cst1[256];
    __shared__ float bias0[NCOL], bias1[NCOL], wih0s[NCOL], wlins[NU];
    __shared__ float xcol[MR];
    __shared__ float blin_s;

    // ---- one-time init ----
    for (int i = tid; i < NCOL*256; i += 256) {
        int n = i >> 8, k = i & 255;
        int r = (n >> 4) * 256 + u0 + (n & 15);            // global gate row
        W0 [n*KP+k] = __float2bfloat16(Whh0[r*256+k]);
        W1i[n*KP+k] = __float2bfloat16(Wih1[r*256+k]);
        W1h[n*KP+k] = __float2bfloat16(Whh1[r*256+k]);
    }
    if (tid < NCOL) {
        int r = (tid >> 4)*256 + u0 + (tid & 15);
        bias0[tid] = bih0[r] + bhh0[r];
        bias1[tid] = bih1[r] + bhh1[r];
        wih0s[tid] = Wih0[r];
    }
    if (tid < NU) wlins[tid] = Wlin[u0+tid];
    if (tid == 0) blin_s = blin[0];
    cst0[tid] = 0.f; cst1[tid] = 0.f;
    {   // zero h buffers p=0 for this cluster (redundant across j, benign)
        uint32_t* z0 = h0w + (0*NC + c)*MR*128;
        uint32_t* z1 = h1w + (0*NC + c)*MR*128;
        for (int i = tid; i < MR*128; i += 256) { st_ic(z0+i, 0u); st_ic(z1+i, 0u); }
    }

    int ph = 1;
    cluster_barrier(slots, j, ph++, tid);

    // ---- fragment geometry (16x16x32 bf16) ----
    const int lane = tid & 63, wave = tid >> 6;
    const int arow = lane & 15;                 // batch row
    const int kq   = (lane >> 4) << 3;          // k sub-offset
    const int bcol = wave*16 + arow;            // local gate col (wave = col tile)
    const int drow = (lane >> 4) << 2;          // D row base
    const __hip_bfloat16* Bw0  = &W0 [bcol*KP];
    const __hip_bfloat16* Bw1i = &W1i[bcol*KP];
    const __hip_bfloat16* Bw1h = &W1h[bcol*KP];
    const __hip_bfloat16* A0p  = (const __hip_bfloat16*)hs0 + arow*KP;
    const __hip_bfloat16* A1p  = (const __hip_bfloat16*)hs1 + arow*KP;
    const int em = tid >> 4, eu = tid & 15;     // elementwise (row, unit)

    for (int t = 0; t < TT; ++t) {
        const int p = t & 1;

        // ===== phase A: stage h0(t-1), h1(t-1) from IC -> LDS =====
        const uint32_t* s0 = h0w + ((p*NC + c)*MR)*128;
        const uint32_t* s1 = h1w + ((p*NC + c)*MR)*128;
        #pragma unroll
        for (int i = 0; i < 8; ++i) {
            int idx = tid + i*256;
            int m = idx >> 7, k = idx & 127;
            hs0[m*132 + k] = ld_ic(s0 + idx);
            hs1[m*132 + k] = ld_ic(s1 + idx);
        }
        if (tid < MR) xcol[tid] = x[(c*MR + tid)*TT + t];

        // WG0: reduce out partials of step t-1 (off critical path, fp32)
        if (t > 0 && j == 0) {
            int jj = tid & 15, rm = tid >> 4;
            float v = ldf_ic(&op[((p*NC + c)*WPC + jj)*MR + rm]);
            v += __shfl_down(v, 8, 16);
            v += __shfl_down(v, 4, 16);
            v += __shfl_down(v, 2, 16);
            v += __shfl_down(v, 1, 16);
            if (jj == 0) out[(c*MR + rm)*TT + (t-1)] = v + blin_s;
        }
        __syncthreads();

        // gates0 tile + layer1 recurrent partial (2 indep chains x2)
        ffrag g0a = {0.f,0.f,0.f,0.f}, g0b = {0.f,0.f,0.f,0.f};
        ffrag g1a = {0.f,0.f,0.f,0.f}, g1b = {0.f,0.f,0.f,0.f};
        #pragma unroll
        for (int ko = 0; ko < 256; ko += 64) {
            g0a = __builtin_amdgcn_mfma_f32_16x16x32_bf16(*(const bfrag*)(A0p+ko+kq),    *(const bfrag*)(Bw0 +ko+kq),    g0a,0,0,0);
            g1a = __builtin_amdgcn_mfma_f32_16x16x32_bf16(*(const bfrag*)(A1p+ko+kq),    *(const bfrag*)(Bw1h+ko+kq),    g1a,0,0,0);
            g0b = __builtin_amdgcn_mfma_f32_16x16x32_bf16(*(const bfrag*)(A0p+ko+32+kq), *(const bfrag*)(Bw0 +ko+32+kq), g0b,0,0,0);
            g1b = __builtin_amdgcn_mfma_f32_16x16x32_bf16(*(const bfrag*)(A1p+ko+32+kq), *(const bfrag*)(Bw1h+ko+32+kq), g1b,0,0,0);
        }
        g0a += g0b;
        #pragma unroll
        for (int i = 0; i < 4; ++i) gbuf[(drow+i)*68 + bcol] = g0a[i];
        __syncthreads();

        // elementwise layer0 -> publish h0_new (packed bf16x2, IC atomics)
        uint32_t* d0 = h0w + (((1-p)*NC + c)*MR)*128;
        {
            float xv = xcol[em];
            float gi = gbuf[em*68 +      eu] + xv*wih0s[     eu] + bias0[     eu];
            float gf = gbuf[em*68 + 16 + eu] + xv*wih0s[16 + eu] + bias0[16 + eu];
            float gg = gbuf[em*68 + 32 + eu] + xv*wih0s[32 + eu] + bias0[32 + eu];
            float go = gbuf[em*68 + 48 + eu] + xv*wih0s[48 + eu] + bias0[48 + eu];
            float cn = sigf(gf)*cst0[tid] + sigf(gi)*tanhfast(gg);
            cst0[tid] = cn;
            float hn = sigf(go)*tanhfast(cn);
            float hn2 = __shfl_xor(hn, 1);
            if ((eu & 1) == 0) {
                __hip_bfloat16 lo = __float2bfloat16(hn), hi = __float2bfloat16(hn2);
                uint32_t pk = ((uint32_t)(*(uint16_t*)&hi) << 16) | (uint32_t)(*(uint16_t*)&lo);
                st_ic(d0 + em*128 + (u0 >> 1) + (eu >> 1), pk);
            }
        }
        cluster_barrier(slots, j, ph++, tid);

        // ===== phase B: stage h0_new, finish layer1 gates =====
        #pragma unroll
        for (int i = 0; i < 8; ++i) {
            int idx = tid + i*256;
            int m = idx >> 7, k = idx & 127;
            hs0[m*132 + k] = ld_ic(d0 + idx);
        }
        __syncthreads();
        #pragma unroll
        for (int ko = 0; ko < 256; ko += 64) {
            g1a = __builtin_amdgcn_mfma_f32_16x16x32_bf16(*(const bfrag*)(A0p+ko+kq),    *(const bfrag*)(Bw1i+ko+kq),    g1a,0,0,0);
            g1b = __builtin_amdgcn_mfma_f32_16x16x32_bf16(*(const bfrag*)(A0p+ko+32+kq), *(const bfrag*)(Bw1i+ko+32+kq), g1b,0,0,0);
        }
        g1a += g1b;
        #pragma unroll
        for (int i = 0; i < 4; ++i) gbuf[(drow+i)*68 + bcol] = g1a[i];
        __syncthreads();

        // elementwise layer1 -> publish h1_new + out partial (fp32)
        uint32_t* d1 = h1w + (((1-p)*NC + c)*MR)*128;
        {
            float gi = gbuf[em*68 +      eu] + bias1[     eu];
            float gf = gbuf[em*68 + 16 + eu] + bias1[16 + eu];
            float gg = gbuf[em*68 + 32 + eu] + bias1[32 + eu];
            float go = gbuf[em*68 + 48 + eu] + bias1[48 + eu];
            float cn = sigf(gf)*cst1[tid] + sigf(gi)*tanhfast(gg);
            cst1[tid] = cn;
            float hn = sigf(go)*tanhfast(cn);
            float hn2 = __shfl_xor(hn, 1);
            if ((eu & 1) == 0) {
                __hip_bfloat16 lo = __float2bfloat16(hn), hi = __float2bfloat16(hn2);
                uint32_t pk = ((uint32_t)(*(uint16_t*)&hi) << 16) | (uint32_t)(*(uint16_t*)&lo);
                st_ic(d1 + em*128 + (u0 >> 1) + (eu >> 1), pk);
            }
            float pv = hn * wlins[eu];
            pv += __shfl_down(pv, 8, 16);
            pv += __shfl_down(pv, 4, 16);
            pv += __shfl_down(pv, 2, 16);
            pv += __shfl_down(pv, 1, 16);
            if (eu == 0)
                stf_ic(&op[(((1-p)*NC + c)*WPC + j)*MR + em], pv);
        }
        cluster_barrier(slots, j, ph++, tid);
    }

    // tail: out column TT-1 (partials live in buffer 0 since TT is even)
    if (j == 0) {
        int jj = tid & 15, rm = tid >> 4;
        float v = ldf_ic(&op[((0*NC + c)*WPC + jj)*MR + rm]);
        v += __shfl_down(v, 8, 16);
        v += __shfl_down(v, 4, 16);
        v += __shfl_down(v, 2, 16);
        v += __shfl_down(v, 1, 16);
        if (jj == 0) out[(c*MR + rm)*TT + (TT-1)] = v + blin_s;
    }
}

extern "C" void kernel_launch(void* const* d_in, const int* in_sizes, int n_in,
                              void* d_out, int out_size, void* d_ws, size_t ws_size,
                              hipStream_t stream)
{
    const float* x    = (const float*)d_in[0];
    const float* Wih0 = (const float*)d_in[1];
    const float* Whh0 = (const float*)d_in[2];
    const float* bih0 = (const float*)d_in[3];
    const float* bhh0 = (const float*)d_in[4];
    const float* Wih1 = (const float*)d_in[5];
    const float* Whh1 = (const float*)d_in[6];
    const float* bih1 = (const float*)d_in[7];
    const float* bhh1 = (const float*)d_in[8];
    const float* Wlin = (const float*)d_in[9];
    const float* blin = (const float*)d_in[10];
    float* out = (float*)d_out;
    char* ws   = (char*)d_ws;

    // 256 blocks x 256 threads, 1 block/CU -> all co-resident (spin barriers safe)
    lstm_kernel<<<dim3(256), dim3(256), 0, stream>>>(
        x, Wih0, Whh0, bih0, bhh0, Wih1, Whh1, bih1, bhh1, Wlin, blin, out, ws);
}

// Round 3
// 4297.096 us; speedup vs baseline: 11.0603x; 2.3730x over previous
//
#include <hip/hip_runtime.h>
#include <hip/hip_bf16.h>
#include <stdint.h>

// ---------------------------------------------------------------------------
// 2-layer LSTM (B=256, T=1024, H=256), persistent clusters, ONE barrier/step.
//
// 16 clusters x 16 batch rows. Cluster = 16 WGs: j<8 = "L0" WGs (layer0, own
// 32 hidden units each), j>=8 = "L1" WGs (layer1, one step behind: at loop
// iter t they compute h1(t-1) from h0(t-1) [published last iter] and h1(t-2)).
// This pipelining needs only ONE cluster barrier per iteration.
//
// R2 post-mortem: __hip_atomic_load staging was chain-serialized by LLVM
// (24 x ~600cy IC round-trips = the whole 10 us/step). Fix: staging now uses
// __builtin_amdgcn_global_load_lds(16B, aux=SC0|SC1=0x11) -> pipelined
// direct-to-LDS loads that bypass L1/L2 (read at IC = coherence point).
// LDS layout is MFMA-fragment-tiled ([ktile][lane][16B]) so all fragment
// reads are dense ds_read_b128 (no bank conflicts). Weights pre-tiled the
// same way at init. Cell state in registers; x in LDS fp32; h exchanged as
// packed bf16 via relaxed agent atomics (1 store/thread -> not serialized).
// ---------------------------------------------------------------------------

#define TT   1024
#define NC   16
#define WPC  16
#define MR   16

typedef __attribute__((ext_vector_type(8))) short  bfrag;
typedef __attribute__((ext_vector_type(4))) float  ffrag;

__device__ __forceinline__ float sigf(float v){ return 1.f/(1.f+__expf(-v)); }
__device__ __forceinline__ float tanhfast(float v){
    v = fminf(fmaxf(v,-15.f),15.f);
    float e = __expf(2.f*v);
    return (e-1.f)/(e+1.f);
}
__device__ __forceinline__ void st_ic(uint32_t* p, uint32_t v){
    __hip_atomic_store(p, v, __ATOMIC_RELAXED, __HIP_MEMORY_SCOPE_AGENT);
}
__device__ __forceinline__ float ldf_ic(const float* p){
    return __hip_atomic_load((float*)p, __ATOMIC_RELAXED, __HIP_MEMORY_SCOPE_AGENT);
}
__device__ __forceinline__ void stf_ic(float* p, float v){
    __hip_atomic_store(p, v, __ATOMIC_RELAXED, __HIP_MEMORY_SCOPE_AGENT);
}

// Pipelined direct-to-LDS stage of one 16x32 bf16 A-tile (1 KB), fragment
// order: LDS gets [lane][16B]. Global h is row-major [m][256] bf16 (128 dw).
// aux=0x11 (SC0|SC1): bypass L1+L2, read at IC (device coherence point).
__device__ __forceinline__ void stage_tile(uint32_t* ldsbase, const uint32_t* hsrc,
                                           int kt, int lane){
    const uint32_t* g = hsrc + ((lane & 15) << 7) + (kt << 4) + ((lane >> 4) << 2);
    uint32_t* l = ldsbase + (kt << 8);          // wave-uniform (+lane*16 implicit)
    __builtin_amdgcn_global_load_lds(
        (const __attribute__((address_space(1))) uint32_t*)(uintptr_t)g,
        (__attribute__((address_space(3))) uint32_t*)(uint32_t)(uintptr_t)l,
        16, 0, 0x11);
}

__device__ __forceinline__ void cluster_barrier(int* slots, int j, int phase, int tid){
    __asm__ volatile("s_waitcnt vmcnt(0)" ::: "memory");
    __syncthreads();
    if (tid == 0)
        __hip_atomic_store(&slots[j], phase, __ATOMIC_RELAXED, __HIP_MEMORY_SCOPE_AGENT);
    if (tid < WPC) {
        while ((int)(__hip_atomic_load(&slots[tid], __ATOMIC_RELAXED, __HIP_MEMORY_SCOPE_AGENT) - phase) < 0) {}
    }
    __asm__ volatile("" ::: "memory");
    __syncthreads();
}

__global__ void __launch_bounds__(256, 1)
lstm_kernel(const float* __restrict__ x,
            const float* __restrict__ Wih0, const float* __restrict__ Whh0,
            const float* __restrict__ bih0, const float* __restrict__ bhh0,
            const float* __restrict__ Wih1, const float* __restrict__ Whh1,
            const float* __restrict__ bih1, const float* __restrict__ bhh1,
            const float* __restrict__ Wlin, const float* __restrict__ blin,
            float* __restrict__ out, char* __restrict__ ws)
{
    const int tid = threadIdx.x;
    const int wg  = blockIdx.x;
    const int c   = wg >> 4;
    const int j   = wg & 15;
    const bool isL0 = (j < 8);
    const int u0 = (isL0 ? j : (j - 8)) * 32;   // first owned hidden unit

    int*      slots = (int*)ws + c * 64;
    uint32_t* h0w   = (uint32_t*)(ws + 16384);            // [2][NC][MR][128] dw (bf16x2)
    uint32_t* h1w   = h0w + 2 * NC * MR * 128;
    float*    op    = (float*)(h1w + 2 * NC * MR * 128);  // [2][NC][8][16]

    // ---- LDS carve (157 KB static) ----
    __shared__ __attribute__((aligned(16))) char S[157056];
    __hip_bfloat16* Wt   = (__hip_bfloat16*)S;             // L0: Whh0-tiled; L1: Wih1-tiled (64 KB)
    __hip_bfloat16* Wt2  = (__hip_bfloat16*)(S + 65536);   // L1: Whh1-tiled (64 KB)
    float*          xs   = (float*)(S + 65536);            // L0: x rows fp32 (aliases Wt2)
    uint32_t*       hs0  = (uint32_t*)(S + 131072);        // staged A tiles (8 KB)
    uint32_t*       hs1  = (uint32_t*)(S + 139264);        // (8 KB, L1 only)
    float*          gbuf = (float*)(S + 147456);           // [16][132] fp32
    float*          biasS= (float*)(S + 155904);           // [128]
    float*          wxS  = (float*)(S + 156416);           // L0: wih0[128]; L1: wlin[32]
    float*          sblin= (float*)(S + 156928);

    // ---- one-time init: weights -> fragment-tiled LDS ----
    {
        const float* Wsrc = isL0 ? Whh0 : Wih1;
        for (int i = tid; i < 128 * 256; i += 256) {
            int n = i >> 8, k = i & 255;                   // local col, K
            int r = (n >> 5) * 256 + u0 + (n & 31);        // global gate row
            int lane = (n & 15) | (((k >> 3) & 3) << 4);
            int toff = ((n >> 4) * 8 + (k >> 5)) * 1024 + lane * 16 + (k & 7) * 2;
            *(__hip_bfloat16*)((char*)Wt + toff) = __float2bfloat16(Wsrc[r * 256 + k]);
            if (!isL0)
                *(__hip_bfloat16*)((char*)Wt2 + toff) = __float2bfloat16(Whh1[r * 256 + k]);
        }
        if (isL0) {  // x slice fp32 -> LDS [m][1024]
            for (int i = tid; i < 16 * 1024; i += 256)
                xs[i] = x[(c * 16 + (i >> 10)) * TT + (i & 1023)];
        }
        if (tid < 128) {
            int r = (tid >> 5) * 256 + u0 + (tid & 31);
            if (isL0) { biasS[tid] = bih0[r] + bhh0[r]; wxS[tid] = Wih0[r]; }
            else      { biasS[tid] = bih1[r] + bhh1[r]; if (tid < 32) wxS[tid] = Wlin[u0 + tid]; }
        }
        if (tid == 0) sblin[0] = blin[0];
        if (tid < 128) {   // zero h buffers parity-1 (read as h(-1))
            st_ic(h0w + (1 * NC + c) * 2048 + j * 128 + tid, 0u);
            st_ic(h1w + (1 * NC + c) * 2048 + j * 128 + tid, 0u);
        }
    }

    // fragment geometry
    const int lane = tid & 63, wave = tid >> 6;
    const int nt0 = wave * 2, nt1 = wave * 2 + 1;          // owned N-tiles
    const int drow = (lane >> 4) * 4, dcol = lane & 15;
    const int em = tid >> 4, up = tid & 15;                // elementwise (row, unit-pair)

    float c0a = 0.f, c0b = 0.f;                            // register cell state
    int ph = 1;
    cluster_barrier(slots, j, ph++, tid);

    for (int t = 0; t <= TT; ++t) {
        const uint32_t* h0prev = h0w + (((t + 1) & 1) * NC + c) * 2048;   // h0(t-1)

        if (isL0) {
            if (t < TT) {
                stage_tile(hs0, h0prev, wave,     lane);
                stage_tile(hs0, h0prev, wave + 4, lane);
            }
            // out-reduce column t-2 (independent; overlap with staging latency)
            if (j == 0 && t >= 2 && tid < 128) {
                int m2 = tid >> 3, jj = tid & 7;
                float v = ldf_ic(&op[((t & 1) * NC + c) * 128 + jj * 16 + m2]);
                v += __shfl_down(v, 4, 8);
                v += __shfl_down(v, 2, 8);
                v += __shfl_down(v, 1, 8);
                if (jj == 0) out[(c * 16 + m2) * TT + (t - 2)] = v + sblin[0];
            }
            if (t < TT) {
                __syncthreads();   // drain vmcnt (staging) + LDS visible
                ffrag a0 = {0.f,0.f,0.f,0.f}, a1 = {0.f,0.f,0.f,0.f};
                #pragma unroll
                for (int kt = 0; kt < 8; ++kt) {
                    bfrag av = *(const bfrag*)((const char*)hs0 + kt * 1024 + lane * 16);
                    bfrag b0 = *(const bfrag*)((const char*)Wt + (nt0 * 8 + kt) * 1024 + lane * 16);
                    bfrag b1 = *(const bfrag*)((const char*)Wt + (nt1 * 8 + kt) * 1024 + lane * 16);
                    a0 = __builtin_amdgcn_mfma_f32_16x16x32_bf16(av, b0, a0, 0, 0, 0);
                    a1 = __builtin_amdgcn_mfma_f32_16x16x32_bf16(av, b1, a1, 0, 0, 0);
                }
                #pragma unroll
                for (int i = 0; i < 4; ++i) {
                    gbuf[(drow + i) * 132 + nt0 * 16 + dcol] = a0[i];
                    gbuf[(drow + i) * 132 + nt1 * 16 + dcol] = a1[i];
                }
                __syncthreads();
                // elementwise layer0: 2 units/thread
                float2 g_i = *(float2*)(gbuf + em * 132 +      2 * up);
                float2 g_f = *(float2*)(gbuf + em * 132 + 32 + 2 * up);
                float2 g_g = *(float2*)(gbuf + em * 132 + 64 + 2 * up);
                float2 g_o = *(float2*)(gbuf + em * 132 + 96 + 2 * up);
                float xv = xs[em * 1024 + t];
                float i0 = g_i.x + xv * wxS[     2*up  ] + biasS[     2*up  ];
                float i1 = g_i.y + xv * wxS[     2*up+1] + biasS[     2*up+1];
                float f0 = g_f.x + xv * wxS[32 + 2*up  ] + biasS[32 + 2*up  ];
                float f1 = g_f.y + xv * wxS[32 + 2*up+1] + biasS[32 + 2*up+1];
                float gg0 = g_g.x + xv * wxS[64 + 2*up  ] + biasS[64 + 2*up  ];
                float gg1 = g_g.y + xv * wxS[64 + 2*up+1] + biasS[64 + 2*up+1];
                float o0 = g_o.x + xv * wxS[96 + 2*up  ] + biasS[96 + 2*up  ];
                float o1 = g_o.y + xv * wxS[96 + 2*up+1] + biasS[96 + 2*up+1];
                c0a = sigf(f0) * c0a + sigf(i0) * tanhfast(gg0);
                c0b = sigf(f1) * c0b + sigf(i1) * tanhfast(gg1);
                float hn0 = sigf(o0) * tanhfast(c0a);
                float hn1 = sigf(o1) * tanhfast(c0b);
                __hip_bfloat16 hb0 = __float2bfloat16(hn0), hb1 = __float2bfloat16(hn1);
                uint32_t pk = ((uint32_t)(*(uint16_t*)&hb1) << 16) | (uint32_t)(*(uint16_t*)&hb0);
                uint32_t* h0dst = h0w + (((t & 1)) * NC + c) * 2048;       // h0(t)
                st_ic(h0dst + em * 128 + (u0 >> 1) + up, pk);
            }
        } else {
            if (t >= 1) {
                const uint32_t* h1p2 = h1w + ((t & 1) * NC + c) * 2048;    // h1(t-2)
                stage_tile(hs0, h0prev, wave,     lane);
                stage_tile(hs0, h0prev, wave + 4, lane);
                stage_tile(hs1, h1p2,   wave,     lane);
                stage_tile(hs1, h1p2,   wave + 4, lane);
                __syncthreads();
                ffrag a0 = {0.f,0.f,0.f,0.f}, a1 = {0.f,0.f,0.f,0.f};
                #pragma unroll
                for (int kt = 0; kt < 8; ++kt) {   // gates1 = h0(t-1) @ Wih1
                    bfrag av = *(const bfrag*)((const char*)hs0 + kt * 1024 + lane * 16);
                    bfrag b0 = *(const bfrag*)((const char*)Wt + (nt0 * 8 + kt) * 1024 + lane * 16);
                    bfrag b1 = *(const bfrag*)((const char*)Wt + (nt1 * 8 + kt) * 1024 + lane * 16);
                    a0 = __builtin_amdgcn_mfma_f32_16x16x32_bf16(av, b0, a0, 0, 0, 0);
                    a1 = __builtin_amdgcn_mfma_f32_16x16x32_bf16(av, b1, a1, 0, 0, 0);
                }
                #pragma unroll
                for (int kt = 0; kt < 8; ++kt) {   // += h1(t-2) @ Whh1
                    bfrag av = *(const bfrag*)((const char*)hs1 + kt * 1024 + lane * 16);
                    bfrag b0 = *(const bfrag*)((const char*)Wt2 + (nt0 * 8 + kt) * 1024 + lane * 16);
                    bfrag b1 = *(const bfrag*)((const char*)Wt2 + (nt1 * 8 + kt) * 1024 + lane * 16);
                    a0 = __builtin_amdgcn_mfma_f32_16x16x32_bf16(av, b0, a0, 0, 0, 0);
                    a1 = __builtin_amdgcn_mfma_f32_16x16x32_bf16(av, b1, a1, 0, 0, 0);
                }
                #pragma unroll
                for (int i = 0; i < 4; ++i) {
                    gbuf[(drow + i) * 132 + nt0 * 16 + dcol] = a0[i];
                    gbuf[(drow + i) * 132 + nt1 * 16 + dcol] = a1[i];
                }
                __syncthreads();
                float2 g_i = *(float2*)(gbuf + em * 132 +      2 * up);
                float2 g_f = *(float2*)(gbuf + em * 132 + 32 + 2 * up);
                float2 g_g = *(float2*)(gbuf + em * 132 + 64 + 2 * up);
                float2 g_o = *(float2*)(gbuf + em * 132 + 96 + 2 * up);
                float i0 = g_i.x + biasS[     2*up  ], i1 = g_i.y + biasS[     2*up+1];
                float f0 = g_f.x + biasS[32 + 2*up  ], f1 = g_f.y + biasS[32 + 2*up+1];
                float gg0 = g_g.x + biasS[64 + 2*up ], gg1 = g_g.y + biasS[64 + 2*up+1];
                float o0 = g_o.x + biasS[96 + 2*up  ], o1 = g_o.y + biasS[96 + 2*up+1];
                c0a = sigf(f0) * c0a + sigf(i0) * tanhfast(gg0);
                c0b = sigf(f1) * c0b + sigf(i1) * tanhfast(gg1);
                float hn0 = sigf(o0) * tanhfast(c0a);
                float hn1 = sigf(o1) * tanhfast(c0b);
                __hip_bfloat16 hb0 = __float2bfloat16(hn0), hb1 = __float2bfloat16(hn1);
                uint32_t pk = ((uint32_t)(*(uint16_t*)&hb1) << 16) | (uint32_t)(*(uint16_t*)&hb0);
                uint32_t* h1dst = h1w + ((((t + 1) & 1)) * NC + c) * 2048; // h1(t-1)
                st_ic(h1dst + em * 128 + (u0 >> 1) + up, pk);
                // out partial for column t-1
                float pv = hn0 * wxS[2 * up] + hn1 * wxS[2 * up + 1];
                pv += __shfl_down(pv, 8, 16);
                pv += __shfl_down(pv, 4, 16);
                pv += __shfl_down(pv, 2, 16);
                pv += __shfl_down(pv, 1, 16);
                if (up == 0)
                    stf_ic(&op[(((t + 1) & 1) * NC + c) * 128 + (j - 8) * 16 + em], pv);
            }
        }
        cluster_barrier(slots, j, ph++, tid);
    }

    // tail: column TT-1 (buffer parity (TT+1)&1 == 1)
    if (isL0 && j == 0 && tid < 128) {
        int m2 = tid >> 3, jj = tid & 7;
        float v = ldf_ic(&op[(1 * NC + c) * 128 + jj * 16 + m2]);
        v += __shfl_down(v, 4, 8);
        v += __shfl_down(v, 2, 8);
        v += __shfl_down(v, 1, 8);
        if (jj == 0) out[(c * 16 + m2) * TT + (TT - 1)] = v + sblin[0];
    }
}

extern "C" void kernel_launch(void* const* d_in, const int* in_sizes, int n_in,
                              void* d_out, int out_size, void* d_ws, size_t ws_size,
                              hipStream_t stream)
{
    const float* x    = (const float*)d_in[0];
    const float* Wih0 = (const float*)d_in[1];
    const float* Whh0 = (const float*)d_in[2];
    const float* bih0 = (const float*)d_in[3];
    const float* bhh0 = (const float*)d_in[4];
    const float* Wih1 = (const float*)d_in[5];
    const float* Whh1 = (const float*)d_in[6];
    const float* bih1 = (const float*)d_in[7];
    const float* bhh1 = (const float*)d_in[8];
    const float* Wlin = (const float*)d_in[9];
    const float* blin = (const float*)d_in[10];
    float* out = (float*)d_out;
    char* ws   = (char*)d_ws;

    lstm_kernel<<<dim3(256), dim3(256), 0, stream>>>(
        x, Wih0, Whh0, bih0, bhh0, Wih1, Whh1, bih1, bhh1, Wlin, blin, out, ws);
}

// Round 5
// 4076.787 us; speedup vs baseline: 11.6580x; 1.0540x over previous
//
#include <hip/hip_runtime.h>
#include <hip/hip_bf16.h>
#include <stdint.h>

// ---------------------------------------------------------------------------
// 2-layer LSTM (B=256, T=1024, H=256), persistent clusters, SELF-PACED
// (no cluster barrier), R4 design + explicit per-wave release drains.
//
// 16 clusters x 16 batch rows; cluster = 16 WGs; j<8 = layer0 WGs, j>=8 =
// layer1 WGs (1 iter behind, gated purely by dataflow). Weights LDS-resident,
// MFMA-fragment-tiled. Per WG iteration t:
//   wave-level poll of one 16B flag quad (exactly its 4 producer deps)
//   -> stage h via global_load_lds(16B, sc0|sc1) -> MFMA -> elementwise
//   -> publish h via 8B atomicExch (executes at IC, lines stay resident)
//   -> PER-WAVE s_waitcnt vmcnt(0)  [R4 bug: vmcnt is per-wave; relying on
//      __syncthreads to drain atomic-without-return was not guaranteed ->
//      flag could reach IC before another wave's h-slice -> stale reads,
//      absmax 1.07e-2]
//   -> __syncthreads -> tid0 publishes flag = t+1 (atomicExch).
// Depth-4 h/op buffers give 3-iter slack; flags monotone; 0xAA poison reads
// as negative = "not arrived". Out columns reduced by L0 WG (col&7) 3 iters
// behind; fp32 throughout the epilogue.
// ---------------------------------------------------------------------------

#define TT   1024
#define NC   16
#define MR   16

typedef __attribute__((ext_vector_type(8))) short  bfrag;
typedef __attribute__((ext_vector_type(4))) float  ffrag;
typedef __attribute__((ext_vector_type(4))) int    ifrag;

__device__ __forceinline__ float sigf(float v){ return 1.f/(1.f+__expf(-v)); }
__device__ __forceinline__ float tanhfast(float v){
    v = fminf(fmaxf(v,-15.f),15.f);
    float e = __expf(2.f*v);
    return (e-1.f)/(e+1.f);
}
// IC-resident publication: atomic RMW executes at the Infinity Cache.
__device__ __forceinline__ void pub32(uint32_t* p, uint32_t v){
    __hip_atomic_exchange(p, v, __ATOMIC_RELAXED, __HIP_MEMORY_SCOPE_AGENT);
}
__device__ __forceinline__ void pub64(unsigned long long* p, unsigned long long v){
    __hip_atomic_exchange(p, v, __ATOMIC_RELAXED, __HIP_MEMORY_SCOPE_AGENT);
}
__device__ __forceinline__ void pubf(float* p, float v){
    union { float f; uint32_t u; } x; x.f = v;
    pub32((uint32_t*)p, x.u);
}
__device__ __forceinline__ float ldf_ic(const float* p){
    return __hip_atomic_load((float*)p, __ATOMIC_RELAXED, __HIP_MEMORY_SCOPE_AGENT);
}
// Per-wave release drain: all my outstanding vmem (incl. atomics w/o return)
// completed at the coherence point before I proceed to the barrier.
__device__ __forceinline__ void drain_vmem(){
    __asm__ volatile("s_waitcnt vmcnt(0)" ::: "memory");
}

// Wave-level poll: one dwordx4 (sc0|sc1 -> reads at IC) fetches the 4 flag
// slots this wave depends on. x,y = L0 producers (>= tgtA), z,w = L1 (>= tgtB).
__device__ __forceinline__ void wave_poll(const int* q, int tgtA, int tgtB){
    for (;;) {
        ifrag f;
        __asm__ volatile("global_load_dwordx4 %0, %1, off sc0 sc1\n\t"
                         "s_waitcnt vmcnt(0)"
                         : "=v"(f) : "v"(q) : "memory");
        if (f[0] >= tgtA && f[1] >= tgtA && f[2] >= tgtB && f[3] >= tgtB) break;
        __builtin_amdgcn_s_sleep(1);
    }
}

// Direct-to-LDS stage of one 16x32 bf16 A-tile, MFMA-fragment order.
__device__ __forceinline__ void stage_tile(uint32_t* ldsbase, const uint32_t* hsrc,
                                           int kt, int lane){
    const uint32_t* g = hsrc + ((lane & 15) << 7) + (kt << 4) + ((lane >> 4) << 2);
    uint32_t* l = ldsbase + (kt << 8);
    __builtin_amdgcn_global_load_lds(
        (const __attribute__((address_space(1))) uint32_t*)(uintptr_t)g,
        (__attribute__((address_space(3))) uint32_t*)(uint32_t)(uintptr_t)l,
        16, 0, 0x11);
}

// flag slot permutation: slot(j) = (j&3)*4 + (j>>2)  =>  quad w holds
// {L0 j=w, L0 j=w+4, L1 j=8+w, L1 j=12+w} in dwords 4w..4w+3 — exactly the
// producers whose k-slices wave w stages.
__device__ __forceinline__ int fslot(int j){ return (j & 3) * 4 + (j >> 2); }

__global__ void __launch_bounds__(256, 1)
lstm_kernel(const float* __restrict__ x,
            const float* __restrict__ Wih0, const float* __restrict__ Whh0,
            const float* __restrict__ bih0, const float* __restrict__ bhh0,
            const float* __restrict__ Wih1, const float* __restrict__ Whh1,
            const float* __restrict__ bih1, const float* __restrict__ bhh1,
            const float* __restrict__ Wlin, const float* __restrict__ blin,
            float* __restrict__ out, char* __restrict__ ws)
{
    const int tid = threadIdx.x;
    const int wg  = blockIdx.x;
    const int c   = wg >> 4;
    const int j   = wg & 15;
    const bool isL0 = (j < 8);
    const int u0 = (isL0 ? j : (j - 8)) * 32;

    int*      flags = (int*)(ws + c * 256);                // 16 dwords used
    uint32_t* h0w   = (uint32_t*)(ws + 16384);             // [4][NC][16][128] dw
    uint32_t* h1w   = h0w + 4 * NC * 2048;                 // +512 KB
    float*    op    = (float*)(h1w + 4 * NC * 2048);       // [4][NC][8][16]

    // ---- LDS carve ----
    __shared__ __attribute__((aligned(16))) char S[157056];
    __hip_bfloat16* Wt   = (__hip_bfloat16*)S;             // L0: Whh0; L1: Wih1 (tiled)
    __hip_bfloat16* Wt2  = (__hip_bfloat16*)(S + 65536);   // L1: Whh1 (tiled)
    float*          xs   = (float*)(S + 65536);            // L0: x fp32 (aliases Wt2)
    uint32_t*       hs0  = (uint32_t*)(S + 131072);
    uint32_t*       hs1  = (uint32_t*)(S + 139264);
    float*          gbuf = (float*)(S + 147456);           // [16][132]
    float*          biasS= (float*)(S + 155904);
    float*          wxS  = (float*)(S + 156416);
    float*          sblin= (float*)(S + 156928);

    // ---- one-time init ----
    {
        const float* Wsrc = isL0 ? Whh0 : Wih1;
        for (int i = tid; i < 128 * 256; i += 256) {
            int n = i >> 8, k = i & 255;
            int r = (n >> 5) * 256 + u0 + (n & 31);
            int lane = (n & 15) | (((k >> 3) & 3) << 4);
            int toff = ((n >> 4) * 8 + (k >> 5)) * 1024 + lane * 16 + (k & 7) * 2;
            *(__hip_bfloat16*)((char*)Wt + toff) = __float2bfloat16(Wsrc[r * 256 + k]);
            if (!isL0)
                *(__hip_bfloat16*)((char*)Wt2 + toff) = __float2bfloat16(Whh1[r * 256 + k]);
        }
        if (isL0) {
            for (int i = tid; i < 16 * 1024; i += 256)
                xs[i] = x[(c * 16 + (i >> 10)) * TT + (i & 1023)];
        }
        if (tid < 128) {
            int r = (tid >> 5) * 256 + u0 + (tid & 31);
            if (isL0) { biasS[tid] = bih0[r] + bhh0[r]; wxS[tid] = Wih0[r]; }
            else      { biasS[tid] = bih1[r] + bhh1[r]; if (tid < 32) wxS[tid] = Wlin[u0 + tid]; }
        }
        if (tid == 0) sblin[0] = blin[0];
        // zero h(-1) = slot 3, own unit-slice across 16 rows (IC-resident)
        {
            uint32_t* z = (isL0 ? h0w : h1w) + (3 * NC + c) * 2048;
            int row = tid >> 4, dw = (u0 >> 1) + (tid & 15);
            pub32(z + row * 128 + dw, 0u);
        }
        drain_vmem();                    // per-wave: zeroes completed at IC
        __syncthreads();
        if (tid == 0) pub32((uint32_t*)(flags + fslot(j)), 0u);   // flag = 0
    }

    // fragment geometry
    const int lane = tid & 63, wave = tid >> 6;
    const int nt0 = wave * 2, nt1 = wave * 2 + 1;
    const int drow = (lane >> 4) * 4, dcol = lane & 15;
    const int em = tid >> 4, up = tid & 15;
    const int* myquad = flags + 4 * wave;

    float c0a = 0.f, c0b = 0.f;

    for (int t = 0; t < TT; ++t) {
        if (isL0) {
            // need h0(t-1) slices [L0 quad >= t]; overwrite h0(t-4) safe when
            // all L1 finished staging it [L1 quad >= t-2, collective via barrier]
            wave_poll(myquad, t, t - 2);
            const uint32_t* src = h0w + (((t + 3) & 3) * NC + c) * 2048;   // h0(t-1)
            stage_tile(hs0, src, wave, lane);
            stage_tile(hs0, src, wave + 4, lane);
            __syncthreads();

            // distributed out-reduce: column t-3 handled by WG (t-3)&7
            if (t >= 3 && j == ((t - 3) & 7) && tid < 128) {
                int m = tid >> 3, jj = tid & 7;
                float v = ldf_ic(&op[(((t - 3) & 3) * NC + c) * 128 + jj * 16 + m]);
                v += __shfl_down(v, 4, 8);
                v += __shfl_down(v, 2, 8);
                v += __shfl_down(v, 1, 8);
                if (jj == 0) out[(c * 16 + m) * TT + (t - 3)] = v + sblin[0];
            }

            ffrag a0 = {0.f,0.f,0.f,0.f}, a1 = {0.f,0.f,0.f,0.f};
            #pragma unroll
            for (int kt = 0; kt < 8; ++kt) {
                bfrag av = *(const bfrag*)((const char*)hs0 + kt * 1024 + lane * 16);
                bfrag b0 = *(const bfrag*)((const char*)Wt + (nt0 * 8 + kt) * 1024 + lane * 16);
                bfrag b1 = *(const bfrag*)((const char*)Wt + (nt1 * 8 + kt) * 1024 + lane * 16);
                a0 = __builtin_amdgcn_mfma_f32_16x16x32_bf16(av, b0, a0, 0, 0, 0);
                a1 = __builtin_amdgcn_mfma_f32_16x16x32_bf16(av, b1, a1, 0, 0, 0);
            }
            #pragma unroll
            for (int i = 0; i < 4; ++i) {
                gbuf[(drow + i) * 132 + nt0 * 16 + dcol] = a0[i];
                gbuf[(drow + i) * 132 + nt1 * 16 + dcol] = a1[i];
            }
            __syncthreads();

            float2 g_i = *(float2*)(gbuf + em * 132 +      2 * up);
            float2 g_f = *(float2*)(gbuf + em * 132 + 32 + 2 * up);
            float2 g_g = *(float2*)(gbuf + em * 132 + 64 + 2 * up);
            float2 g_o = *(float2*)(gbuf + em * 132 + 96 + 2 * up);
            float xv = xs[em * 1024 + t];
            float i0 = g_i.x + xv * wxS[     2*up  ] + biasS[     2*up  ];
            float i1 = g_i.y + xv * wxS[     2*up+1] + biasS[     2*up+1];
            float f0 = g_f.x + xv * wxS[32 + 2*up  ] + biasS[32 + 2*up  ];
            float f1 = g_f.y + xv * wxS[32 + 2*up+1] + biasS[32 + 2*up+1];
            float gg0 = g_g.x + xv * wxS[64 + 2*up  ] + biasS[64 + 2*up  ];
            float gg1 = g_g.y + xv * wxS[64 + 2*up+1] + biasS[64 + 2*up+1];
            float o0 = g_o.x + xv * wxS[96 + 2*up  ] + biasS[96 + 2*up  ];
            float o1 = g_o.y + xv * wxS[96 + 2*up+1] + biasS[96 + 2*up+1];
            c0a = sigf(f0) * c0a + sigf(i0) * tanhfast(gg0);
            c0b = sigf(f1) * c0b + sigf(i1) * tanhfast(gg1);
            float hn0 = sigf(o0) * tanhfast(c0a);
            float hn1 = sigf(o1) * tanhfast(c0b);
            __hip_bfloat16 hb0 = __float2bfloat16(hn0), hb1 = __float2bfloat16(hn1);
            uint32_t pk = ((uint32_t)(*(uint16_t*)&hb1) << 16) | (uint32_t)(*(uint16_t*)&hb0);
            uint32_t nb = __shfl_down(pk, 1);
            if ((up & 1) == 0) {
                unsigned long long v = (unsigned long long)pk |
                                       ((unsigned long long)nb << 32);
                pub64((unsigned long long*)
                      (h0w + ((t & 3) * NC + c) * 2048 + em * 128 + (u0 >> 1) + up), v);
            }
            drain_vmem();                // per-wave: my h-slice ack'd at IC
            __syncthreads();             // => ALL waves' slices ack'd
            if (tid == 0) pub32((uint32_t*)(flags + fslot(j)), (uint32_t)(t + 1));
        } else {
            // need h0(t) [L0 quad >= t+1] and h1(t-1) [L1 quad >= t]
            wave_poll(myquad, t + 1, t);
            const uint32_t* s0 = h0w + ((t & 3) * NC + c) * 2048;          // h0(t)
            const uint32_t* s1 = h1w + (((t + 3) & 3) * NC + c) * 2048;    // h1(t-1)
            stage_tile(hs0, s0, wave, lane);
            stage_tile(hs0, s0, wave + 4, lane);
            stage_tile(hs1, s1, wave, lane);
            stage_tile(hs1, s1, wave + 4, lane);
            __syncthreads();

            ffrag a0 = {0.f,0.f,0.f,0.f}, a1 = {0.f,0.f,0.f,0.f};
            #pragma unroll
            for (int kt = 0; kt < 8; ++kt) {       // h0(t) @ Wih1
                bfrag av = *(const bfrag*)((const char*)hs0 + kt * 1024 + lane * 16);
                bfrag b0 = *(const bfrag*)((const char*)Wt + (nt0 * 8 + kt) * 1024 + lane * 16);
                bfrag b1 = *(const bfrag*)((const char*)Wt + (nt1 * 8 + kt) * 1024 + lane * 16);
                a0 = __builtin_amdgcn_mfma_f32_16x16x32_bf16(av, b0, a0, 0, 0, 0);
                a1 = __builtin_amdgcn_mfma_f32_16x16x32_bf16(av, b1, a1, 0, 0, 0);
            }
            #pragma unroll
            for (int kt = 0; kt < 8; ++kt) {       // += h1(t-1) @ Whh1
                bfrag av = *(const bfrag*)((const char*)hs1 + kt * 1024 + lane * 16);
                bfrag b0 = *(const bfrag*)((const char*)Wt2 + (nt0 * 8 + kt) * 1024 + lane * 16);
                bfrag b1 = *(const bfrag*)((const char*)Wt2 + (nt1 * 8 + kt) * 1024 + lane * 16);
                a0 = __builtin_amdgcn_mfma_f32_16x16x32_bf16(av, b0, a0, 0, 0, 0);
                a1 = __builtin_amdgcn_mfma_f32_16x16x32_bf16(av, b1, a1, 0, 0, 0);
            }
            #pragma unroll
            for (int i = 0; i < 4; ++i) {
                gbuf[(drow + i) * 132 + nt0 * 16 + dcol] = a0[i];
                gbuf[(drow + i) * 132 + nt1 * 16 + dcol] = a1[i];
            }
            __syncthreads();

            float2 g_i = *(float2*)(gbuf + em * 132 +      2 * up);
            float2 g_f = *(float2*)(gbuf + em * 132 + 32 + 2 * up);
            float2 g_g = *(float2*)(gbuf + em * 132 + 64 + 2 * up);
            float2 g_o = *(float2*)(gbuf + em * 132 + 96 + 2 * up);
            float i0 = g_i.x + biasS[     2*up  ], i1 = g_i.y + biasS[     2*up+1];
            float f0 = g_f.x + biasS[32 + 2*up  ], f1 = g_f.y + biasS[32 + 2*up+1];
            float gg0 = g_g.x + biasS[64 + 2*up ], gg1 = g_g.y + biasS[64 + 2*up+1];
            float o0 = g_o.x + biasS[96 + 2*up  ], o1 = g_o.y + biasS[96 + 2*up+1];
            c0a = sigf(f0) * c0a + sigf(i0) * tanhfast(gg0);
            c0b = sigf(f1) * c0b + sigf(i1) * tanhfast(gg1);
            float hn0 = sigf(o0) * tanhfast(c0a);
            float hn1 = sigf(o1) * tanhfast(c0b);
            __hip_bfloat16 hb0 = __float2bfloat16(hn0), hb1 = __float2bfloat16(hn1);
            uint32_t pk = ((uint32_t)(*(uint16_t*)&hb1) << 16) | (uint32_t)(*(uint16_t*)&hb0);
            uint32_t nb = __shfl_down(pk, 1);
            if ((up & 1) == 0) {
                unsigned long long v = (unsigned long long)pk |
                                       ((unsigned long long)nb << 32);
                pub64((unsigned long long*)
                      (h1w + ((t & 3) * NC + c) * 2048 + em * 128 + (u0 >> 1) + up), v);
            }
            // out partial for column t (fp32)
            float pv = hn0 * wxS[2 * up] + hn1 * wxS[2 * up + 1];
            pv += __shfl_down(pv, 8, 16);
            pv += __shfl_down(pv, 4, 16);
            pv += __shfl_down(pv, 2, 16);
            pv += __shfl_down(pv, 1, 16);
            if (up == 0)
                pubf(&op[((t & 3) * NC + c) * 128 + (j - 8) * 16 + em], pv);
            drain_vmem();                // per-wave: h + op ack'd at IC
            __syncthreads();
            if (tid == 0) pub32((uint32_t*)(flags + fslot(j)), (uint32_t)(t + 1));
        }
    }

    // tail: columns TT-3..TT-1 by L0 WGs 5,6,7 ((col)&7 == j)
    if (isL0 && j >= 5) {
        wave_poll(myquad, 0, TT);        // collective: all L1 finished iter TT-1
        __syncthreads();
        int col = TT - 8 + j;            // 1021,1022,1023
        if (tid < 128) {
            int m = tid >> 3, jj = tid & 7;
            float v = ldf_ic(&op[((col & 3) * NC + c) * 128 + jj * 16 + m]);
            v += __shfl_down(v, 4, 8);
            v += __shfl_down(v, 2, 8);
            v += __shfl_down(v, 1, 8);
            if (jj == 0) out[(c * 16 + m) * TT + col] = v + sblin[0];
        }
    }
}

extern "C" void kernel_launch(void* const* d_in, const int* in_sizes, int n_in,
                              void* d_out, int out_size, void* d_ws, size_t ws_size,
                              hipStream_t stream)
{
    const float* x    = (const float*)d_in[0];
    const float* Wih0 = (const float*)d_in[1];
    const float* Whh0 = (const float*)d_in[2];
    const float* bih0 = (const float*)d_in[3];
    const float* bhh0 = (const float*)d_in[4];
    const float* Wih1 = (const float*)d_in[5];
    const float* Whh1 = (const float*)d_in[6];
    const float* bih1 = (const float*)d_in[7];
    const float* bhh1 = (const float*)d_in[8];
    const float* Wlin = (const float*)d_in[9];
    const float* blin = (const float*)d_in[10];
    float* out = (float*)d_out;
    char* ws   = (char*)d_ws;

    lstm_kernel<<<dim3(256), dim3(256), 0, stream>>>(
        x, Wih0, Whh0, bih0, bhh0, Wih1, Whh1, bih1, bhh1, Wlin, blin, out, ws);
}

// Round 8
// 3224.617 us; speedup vs baseline: 14.7389x; 1.2643x over previous
//
#include <hip/hip_runtime.h>
#include <hip/hip_bf16.h>
#include <stdint.h>

// ---------------------------------------------------------------------------
// 2-layer LSTM (B=256, T=1024, H=256), persistent clusters, self-paced
// dataflow. R5-proven protocol + DE-CONTENDED exchange lines.
//
// R5 post-mortem: modeled chain ~2us/step, measured 3.9 -> the unmodeled term
// is line contention: all 16 flags in ONE 128B line absorbing 16 RMWs + ~64
// polling reads per step (same-line ops serialize at the IC). R6/R7's
// XCD-local formation (s_getreg + memset + rendezvous) died with infra
// exceptions twice -> dropped entirely; nothing in this kernel can hang.
//
// Changes vs R5 (body/protocol otherwise identical):
//  1. One flag per WG on a PRIVATE 128B line (ws + c*4096 + j*128). A wave's
//     poll = 4 independent dword loads (4 distinct lines, one vmcnt wait),
//     same thresholds as R5.
//  2. h state in per-producer 1KB blocks [slot][c][prod][row16][32units]
//     (k-tile kt <-> producer kt), published with plain relaxed-agent stores
//     (R3-proven: store -> per-wave vmcnt drain -> barrier -> flag store).
//     No cross-WG cache-line sharing, no atomic RMWs on data.
//  3. op partials plain stores.
// ---------------------------------------------------------------------------

#define TT   1024
#define NC   16
#define MR   16

typedef __attribute__((ext_vector_type(8))) short  bfrag;
typedef __attribute__((ext_vector_type(4))) float  ffrag;

__device__ __forceinline__ float sigf(float v){ return 1.f/(1.f+__expf(-v)); }
__device__ __forceinline__ float tanhfast(float v){
    v = fminf(fmaxf(v,-15.f),15.f);
    float e = __expf(2.f*v);
    return (e-1.f)/(e+1.f);
}
// Plain device-coherent publishes (R3-proven visibility protocol).
__device__ __forceinline__ void st32(uint32_t* p, uint32_t v){
    __hip_atomic_store(p, v, __ATOMIC_RELAXED, __HIP_MEMORY_SCOPE_AGENT);
}
__device__ __forceinline__ void st64(unsigned long long* p, unsigned long long v){
    __hip_atomic_store(p, v, __ATOMIC_RELAXED, __HIP_MEMORY_SCOPE_AGENT);
}
__device__ __forceinline__ void stf(float* p, float v){
    __hip_atomic_store(p, v, __ATOMIC_RELAXED, __HIP_MEMORY_SCOPE_AGENT);
}
__device__ __forceinline__ float ldf_coh(const float* p){
    float v;
    __asm__ volatile("global_load_dword %0, %1, off sc0 sc1\n\ts_waitcnt vmcnt(0)"
                     : "=v"(v) : "v"(p) : "memory");
    return v;
}
// Per-wave release drain (vmcnt is per-wave; EVERY wave must drain before the
// flag-publishing barrier — R4 lesson).
__device__ __forceinline__ void drain_vmem(){
    __asm__ volatile("s_waitcnt vmcnt(0)" ::: "memory");
}

// Poll 4 flags on 4 DISTINCT cache lines (parallel loads, one wait).
// a,b = L0 producers (>= tgtA); c,d = L1 producers (>= tgtB).
__device__ __forceinline__ void wave_poll(const int* fa, const int* fb,
                                          const int* fc, const int* fd,
                                          int tgtA, int tgtB){
    for (;;) {
        int a, b, c, d;
        __asm__ volatile(
            "global_load_dword %0, %4, off sc0 sc1\n\t"
            "global_load_dword %1, %5, off sc0 sc1\n\t"
            "global_load_dword %2, %6, off sc0 sc1\n\t"
            "global_load_dword %3, %7, off sc0 sc1\n\t"
            "s_waitcnt vmcnt(0)"
            : "=&v"(a), "=&v"(b), "=&v"(c), "=&v"(d)
            : "v"(fa), "v"(fb), "v"(fc), "v"(fd) : "memory");
        if (a >= tgtA && b >= tgtA && c >= tgtB && d >= tgtB) break;
        __builtin_amdgcn_s_sleep(1);
    }
}

// Direct-to-LDS stage of one 16x32 bf16 A-tile from a per-producer 1KB block.
// Block layout: [row(16)][32 units bf16] = row stride 16 dw. MFMA-fragment
// order in LDS: [lane][16B].
__device__ __forceinline__ void stage_tile(uint32_t* ldsbase, const uint32_t* hblocks,
                                           int kt, int lane){
    const uint32_t* g = hblocks + (kt << 8) + ((lane & 15) << 4) + ((lane >> 4) << 2);
    uint32_t* l = ldsbase + (kt << 8);
    __builtin_amdgcn_global_load_lds(
        (const __attribute__((address_space(1))) uint32_t*)(uintptr_t)g,
        (__attribute__((address_space(3))) uint32_t*)(uint32_t)(uintptr_t)l,
        16, 0, 0x11);
}

__global__ void __launch_bounds__(256, 1)
lstm_kernel(const float* __restrict__ x,
            const float* __restrict__ Wih0, const float* __restrict__ Whh0,
            const float* __restrict__ bih0, const float* __restrict__ bhh0,
            const float* __restrict__ Wih1, const float* __restrict__ Whh1,
            const float* __restrict__ bih1, const float* __restrict__ bhh1,
            const float* __restrict__ Wlin, const float* __restrict__ blin,
            float* __restrict__ out, char* __restrict__ ws)
{
    const int tid = threadIdx.x;
    const int wg  = blockIdx.x;
    const int c   = wg >> 4;
    const int j   = wg & 15;
    const bool isL0 = (j < 8);
    const int  u0   = (isL0 ? j : (j - 8)) * 32;

    // flags: 16 clusters x 16 WGs x 128B private lines = 64 KB
    int* flagbase = (int*)(ws + c * 4096);
    // h: [4 slots][NC][8 producers][16 rows][32 units bf16] = 512 KB each
    uint32_t* h0w = (uint32_t*)(ws + 65536);
    uint32_t* h1w = h0w + 4 * NC * 8 * 256;
    float*    op  = (float*)(h1w + 4 * NC * 8 * 256);    // [4][NC][8][16] fp32

    // ---- LDS carve ----
    __shared__ __attribute__((aligned(16))) char S[157056];
    __hip_bfloat16* Wt   = (__hip_bfloat16*)S;           // L0: Whh0; L1: Wih1 (tiled)
    __hip_bfloat16* Wt2  = (__hip_bfloat16*)(S + 65536); // L1: Whh1 (tiled)
    float*          xs   = (float*)(S + 65536);          // L0: x fp32 (aliases Wt2)
    uint32_t*       hs0  = (uint32_t*)(S + 131072);
    uint32_t*       hs1  = (uint32_t*)(S + 139264);
    float*          gbuf = (float*)(S + 147456);         // [16][132]
    float*          biasS= (float*)(S + 155904);
    float*          wxS  = (float*)(S + 156416);
    float*          sblin= (float*)(S + 156928);

    // ---- one-time init ----
    {
        const float* Wsrc = isL0 ? Whh0 : Wih1;
        for (int i = tid; i < 128 * 256; i += 256) {
            int n = i >> 8, k = i & 255;
            int r = (n >> 5) * 256 + u0 + (n & 31);
            int lane = (n & 15) | (((k >> 3) & 3) << 4);
            int toff = ((n >> 4) * 8 + (k >> 5)) * 1024 + lane * 16 + (k & 7) * 2;
            *(__hip_bfloat16*)((char*)Wt + toff) = __float2bfloat16(Wsrc[r * 256 + k]);
            if (!isL0)
                *(__hip_bfloat16*)((char*)Wt2 + toff) = __float2bfloat16(Whh1[r * 256 + k]);
        }
        if (isL0) {
            for (int i = tid; i < 16 * 1024; i += 256)
                xs[i] = x[(c * 16 + (i >> 10)) * TT + (i & 1023)];
        }
        if (tid < 128) {
            int r = (tid >> 5) * 256 + u0 + (tid & 31);
            if (isL0) { biasS[tid] = bih0[r] + bhh0[r]; wxS[tid] = Wih0[r]; }
            else      { biasS[tid] = bih1[r] + bhh1[r]; if (tid < 32) wxS[tid] = Wlin[u0 + tid]; }
        }
        if (tid == 0) sblin[0] = blin[0];
        // zero h(-1) = slot 3: each WG zeroes ITS OWN 1KB block (256 dw)
        {
            uint32_t* z = isL0 ? (h0w + ((3 * NC + c) * 8 + j) * 256)
                               : (h1w + ((3 * NC + c) * 8 + (j - 8)) * 256);
            st32(z + tid, 0u);
        }
        drain_vmem();                    // per-wave: zeroes at coherence point
        __syncthreads();
        if (tid == 0) st32((uint32_t*)(flagbase + j * 32), 0u);   // my flag = 0
    }

    // fragment geometry
    const int lane = tid & 63, wave = tid >> 6;
    const int nt0 = wave * 2, nt1 = wave * 2 + 1;
    const int drow = (lane >> 4) * 4, dcol = lane & 15;
    const int em = tid >> 4, up = tid & 15;
    // my 4 dependency flags, each on a private 128B line
    const int* fL0a = flagbase + (wave)      * 32;
    const int* fL0b = flagbase + (wave + 4)  * 32;
    const int* fL1a = flagbase + (8 + wave)  * 32;
    const int* fL1b = flagbase + (12 + wave) * 32;

    float c0a = 0.f, c0b = 0.f;

    for (int t = 0; t < TT; ++t) {
        if (isL0) {
            // data: h0(t-1) tiles wave,wave+4 [L0 >= t]; overwrite-safety
            // on h0(t-4) [L1 >= t-2, collective via the barriers below]
            wave_poll(fL0a, fL0b, fL1a, fL1b, t, t - 2);
            const uint32_t* src = h0w + (((t + 3) & 3) * NC + c) * 8 * 256;  // h0(t-1)
            stage_tile(hs0, src, wave, lane);
            stage_tile(hs0, src, wave + 4, lane);
            __syncthreads();

            // distributed out-reduce: column t-3 by WG (t-3)&7
            if (t >= 3 && j == ((t - 3) & 7) && tid < 128) {
                int m = tid >> 3, jj = tid & 7;
                float v = ldf_coh(&op[(((t - 3) & 3) * NC + c) * 128 + jj * 16 + m]);
                v += __shfl_down(v, 4, 8);
                v += __shfl_down(v, 2, 8);
                v += __shfl_down(v, 1, 8);
                if (jj == 0) out[(c * 16 + m) * TT + (t - 3)] = v + sblin[0];
            }

            ffrag a0 = {0.f,0.f,0.f,0.f}, a1 = {0.f,0.f,0.f,0.f};
            #pragma unroll
            for (int kt = 0; kt < 8; ++kt) {
                bfrag av = *(const bfrag*)((const char*)hs0 + kt * 1024 + lane * 16);
                bfrag b0 = *(const bfrag*)((const char*)Wt + (nt0 * 8 + kt) * 1024 + lane * 16);
                bfrag b1 = *(const bfrag*)((const char*)Wt + (nt1 * 8 + kt) * 1024 + lane * 16);
                a0 = __builtin_amdgcn_mfma_f32_16x16x32_bf16(av, b0, a0, 0, 0, 0);
                a1 = __builtin_amdgcn_mfma_f32_16x16x32_bf16(av, b1, a1, 0, 0, 0);
            }
            #pragma unroll
            for (int i = 0; i < 4; ++i) {
                gbuf[(drow + i) * 132 + nt0 * 16 + dcol] = a0[i];
                gbuf[(drow + i) * 132 + nt1 * 16 + dcol] = a1[i];
            }
            __syncthreads();

            float2 g_i = *(float2*)(gbuf + em * 132 +      2 * up);
            float2 g_f = *(float2*)(gbuf + em * 132 + 32 + 2 * up);
            float2 g_g = *(float2*)(gbuf + em * 132 + 64 + 2 * up);
            float2 g_o = *(float2*)(gbuf + em * 132 + 96 + 2 * up);
            float xv = xs[em * 1024 + t];
            float i0 = g_i.x + xv * wxS[     2*up  ] + biasS[     2*up  ];
            float i1 = g_i.y + xv * wxS[     2*up+1] + biasS[     2*up+1];
            float f0 = g_f.x + xv * wxS[32 + 2*up  ] + biasS[32 + 2*up  ];
            float f1 = g_f.y + xv * wxS[32 + 2*up+1] + biasS[32 + 2*up+1];
            float gg0 = g_g.x + xv * wxS[64 + 2*up  ] + biasS[64 + 2*up  ];
            float gg1 = g_g.y + xv * wxS[64 + 2*up+1] + biasS[64 + 2*up+1];
            float o0 = g_o.x + xv * wxS[96 + 2*up  ] + biasS[96 + 2*up  ];
            float o1 = g_o.y + xv * wxS[96 + 2*up+1] + biasS[96 + 2*up+1];
            c0a = sigf(f0) * c0a + sigf(i0) * tanhfast(gg0);
            c0b = sigf(f1) * c0b + sigf(i1) * tanhfast(gg1);
            float hn0 = sigf(o0) * tanhfast(c0a);
            float hn1 = sigf(o1) * tanhfast(c0b);
            __hip_bfloat16 hb0 = __float2bfloat16(hn0), hb1 = __float2bfloat16(hn1);
            uint32_t pk = ((uint32_t)(*(uint16_t*)&hb1) << 16) | (uint32_t)(*(uint16_t*)&hb0);
            uint32_t nb = __shfl_down(pk, 1);
            if ((up & 1) == 0) {
                unsigned long long v = (unsigned long long)pk |
                                       ((unsigned long long)nb << 32);
                // my own 1KB block: [row em][dw up..up+1]
                st64((unsigned long long*)
                     (h0w + (((t & 3) * NC + c) * 8 + j) * 256 + em * 16 + up), v);
            }
            drain_vmem();                // per-wave: my h-slice at coherence point
            __syncthreads();             // => ALL waves' slices ack'd
            if (tid == 0) st32((uint32_t*)(flagbase + j * 32), (uint32_t)(t + 1));
        } else {
            // data: h0(t) [L0 >= t+1] and h1(t-1) [L1 >= t]
            wave_poll(fL0a, fL0b, fL1a, fL1b, t + 1, t);
            const uint32_t* s0 = h0w + ((t & 3) * NC + c) * 8 * 256;         // h0(t)
            const uint32_t* s1 = h1w + (((t + 3) & 3) * NC + c) * 8 * 256;   // h1(t-1)
            stage_tile(hs0, s0, wave, lane);
            stage_tile(hs0, s0, wave + 4, lane);
            stage_tile(hs1, s1, wave, lane);
            stage_tile(hs1, s1, wave + 4, lane);
            __syncthreads();

            ffrag a0 = {0.f,0.f,0.f,0.f}, a1 = {0.f,0.f,0.f,0.f};
            #pragma unroll
            for (int kt = 0; kt < 8; ++kt) {       // h0(t) @ Wih1
                bfrag av = *(const bfrag*)((const char*)hs0 + kt * 1024 + lane * 16);
                bfrag b0 = *(const bfrag*)((const char*)Wt + (nt0 * 8 + kt) * 1024 + lane * 16);
                bfrag b1 = *(const bfrag*)((const char*)Wt + (nt1 * 8 + kt) * 1024 + lane * 16);
                a0 = __builtin_amdgcn_mfma_f32_16x16x32_bf16(av, b0, a0, 0, 0, 0);
                a1 = __builtin_amdgcn_mfma_f32_16x16x32_bf16(av, b1, a1, 0, 0, 0);
            }
            #pragma unroll
            for (int kt = 0; kt < 8; ++kt) {       // += h1(t-1) @ Whh1
                bfrag av = *(const bfrag*)((const char*)hs1 + kt * 1024 + lane * 16);
                bfrag b0 = *(const bfrag*)((const char*)Wt2 + (nt0 * 8 + kt) * 1024 + lane * 16);
                bfrag b1 = *(const bfrag*)((const char*)Wt2 + (nt1 * 8 + kt) * 1024 + lane * 16);
                a0 = __builtin_amdgcn_mfma_f32_16x16x32_bf16(av, b0, a0, 0, 0, 0);
                a1 = __builtin_amdgcn_mfma_f32_16x16x32_bf16(av, b1, a1, 0, 0, 0);
            }
            #pragma unroll
            for (int i = 0; i < 4; ++i) {
                gbuf[(drow + i) * 132 + nt0 * 16 + dcol] = a0[i];
                gbuf[(drow + i) * 132 + nt1 * 16 + dcol] = a1[i];
            }
            __syncthreads();

            float2 g_i = *(float2*)(gbuf + em * 132 +      2 * up);
            float2 g_f = *(float2*)(gbuf + em * 132 + 32 + 2 * up);
            float2 g_g = *(float2*)(gbuf + em * 132 + 64 + 2 * up);
            float2 g_o = *(float2*)(gbuf + em * 132 + 96 + 2 * up);
            float i0 = g_i.x + biasS[     2*up  ], i1 = g_i.y + biasS[     2*up+1];
            float f0 = g_f.x + biasS[32 + 2*up  ], f1 = g_f.y + biasS[32 + 2*up+1];
            float gg0 = g_g.x + biasS[64 + 2*up ], gg1 = g_g.y + biasS[64 + 2*up+1];
            float o0 = g_o.x + biasS[96 + 2*up  ], o1 = g_o.y + biasS[96 + 2*up+1];
            c0a = sigf(f0) * c0a + sigf(i0) * tanhfast(gg0);
            c0b = sigf(f1) * c0b + sigf(i1) * tanhfast(gg1);
            float hn0 = sigf(o0) * tanhfast(c0a);
            float hn1 = sigf(o1) * tanhfast(c0b);
            __hip_bfloat16 hb0 = __float2bfloat16(hn0), hb1 = __float2bfloat16(hn1);
            uint32_t pk = ((uint32_t)(*(uint16_t*)&hb1) << 16) | (uint32_t)(*(uint16_t*)&hb0);
            uint32_t nb = __shfl_down(pk, 1);
            if ((up & 1) == 0) {
                unsigned long long v = (unsigned long long)pk |
                                       ((unsigned long long)nb << 32);
                st64((unsigned long long*)
                     (h1w + (((t & 3) * NC + c) * 8 + (j - 8)) * 256 + em * 16 + up), v);
            }
            // out partial for column t (fp32)
            float pv = hn0 * wxS[2 * up] + hn1 * wxS[2 * up + 1];
            pv += __shfl_down(pv, 8, 16);
            pv += __shfl_down(pv, 4, 16);
            pv += __shfl_down(pv, 2, 16);
            pv += __shfl_down(pv, 1, 16);
            if (up == 0)
                stf(&op[((t & 3) * NC + c) * 128 + (j - 8) * 16 + em], pv);
            drain_vmem();                // per-wave: h + op at coherence point
            __syncthreads();
            if (tid == 0) st32((uint32_t*)(flagbase + j * 32), (uint32_t)(t + 1));
        }
    }

    // tail: columns TT-3..TT-1 by L0 WGs 5,6,7 (collective L1>=TT via 4 waves)
    if (isL0 && j >= 5) {
        wave_poll(fL0a, fL0b, fL1a, fL1b, 0, TT);
        __syncthreads();
        int col = TT - 8 + j;            // 1021,1022,1023
        if (tid < 128) {
            int m = tid >> 3, jj = tid & 7;
            float v = ldf_coh(&op[((col & 3) * NC + c) * 128 + jj * 16 + m]);
            v += __shfl_down(v, 4, 8);
            v += __shfl_down(v, 2, 8);
            v += __shfl_down(v, 1, 8);
            if (jj == 0) out[(c * 16 + m) * TT + col] = v + sblin[0];
        }
    }
}

extern "C" void kernel_launch(void* const* d_in, const int* in_sizes, int n_in,
                              void* d_out, int out_size, void* d_ws, size_t ws_size,
                              hipStream_t stream)
{
    const float* x    = (const float*)d_in[0];
    const float* Wih0 = (const float*)d_in[1];
    const float* Whh0 = (const float*)d_in[2];
    const float* bih0 = (const float*)d_in[3];
    const float* bhh0 = (const float*)d_in[4];
    const float* Wih1 = (const float*)d_in[5];
    const float* Whh1 = (const float*)d_in[6];
    const float* bih1 = (const float*)d_in[7];
    const float* bhh1 = (const float*)d_in[8];
    const float* Wlin = (const float*)d_in[9];
    const float* blin = (const float*)d_in[10];
    float* out = (float*)d_out;
    char* ws   = (char*)d_ws;

    // 256 blocks x 256 threads, 1 block/CU -> all co-resident (spin-safe).
    lstm_kernel<<<dim3(256), dim3(256), 0, stream>>>(
        x, Wih0, Whh0, bih0, bhh0, Wih1, Whh1, bih1, bhh1, Wlin, blin, out, ws);
}